// Round 2
// baseline (4250.478 us; speedup 1.0000x reference)
//
#include <hip/hip_runtime.h>
#include <math.h>

#define D_ 128
#define H_ 160
#define W_ 160
#define HW_ (H_ * W_)            // 25600
#define V_ (D_ * H_ * W_)        // 3,276,800
#define SMOOTHF 1e-5

// vol index i in 0..7: 0..3 = pred (b = i>>1, ch = (i&1)+1 of net_output),
//                      4..7 = gt one-hot (b = (i-4)>>1, class (i&1)+1 of target)
__device__ __forceinline__ float load_src(const float* __restrict__ net,
                                          const int* __restrict__ tgt,
                                          int i, int p) {
    if (i < 4) {
        int b = i >> 1, c = (i & 1) + 1;
        return net[(long)(b * 3 + c) * V_ + p];
    } else {
        int j = i - 4;
        int b = j >> 1, c = (j & 1) + 1;
        int t = tgt[(long)b * V_ + p];
        t = t < 0 ? 0 : (t > 2 ? 2 : t);
        return (t == c) ? 1.0f : 0.0f;
    }
}

// e1 = erode(src): 7-point cross min, reading source on the fly
__global__ void erode_src_kernel(const float* __restrict__ net,
                                 const int* __restrict__ tgt,
                                 int i0,
                                 float* __restrict__ out) {
    int j = blockIdx.y;               // local volume in group
    int i = i0 + j;                   // global volume
    int p = blockIdx.x * blockDim.x + threadIdx.x;
    int z = p / HW_;
    int r = p - z * HW_;
    int y = r / W_;
    int x = r - y * W_;
    float m = load_src(net, tgt, i, p);
    if (z > 0)       m = fminf(m, load_src(net, tgt, i, p - HW_));
    if (z < D_ - 1)  m = fminf(m, load_src(net, tgt, i, p + HW_));
    if (y > 0)       m = fminf(m, load_src(net, tgt, i, p - W_));
    if (y < H_ - 1)  m = fminf(m, load_src(net, tgt, i, p + W_));
    if (x > 0)       m = fminf(m, load_src(net, tgt, i, p - 1));
    if (x < W_ - 1)  m = fminf(m, load_src(net, tgt, i, p + 1));
    out[(long)j * V_ + p] = m;
}

// 7-point cross min from a stacked array (local volume indexing)
__global__ void erode_kernel(const float* __restrict__ in,
                             float* __restrict__ out) {
    int j = blockIdx.y;
    int p = blockIdx.x * blockDim.x + threadIdx.x;
    const float* v = in + (long)j * V_;
    int z = p / HW_;
    int r = p - z * HW_;
    int y = r / W_;
    int x = r - y * W_;
    float m = v[p];
    if (z > 0)       m = fminf(m, v[p - HW_]);
    if (z < D_ - 1)  m = fminf(m, v[p + HW_]);
    if (y > 0)       m = fminf(m, v[p - W_]);
    if (y < H_ - 1)  m = fminf(m, v[p + W_]);
    if (x > 0)       m = fminf(m, v[p - 1]);
    if (x < W_ - 1)  m = fminf(m, v[p + 1]);
    out[(long)j * V_ + p] = m;
}

// 27-point max (soft_dilate) of v at (z,y,x) with flat index p
__device__ __forceinline__ float dilate27(const float* __restrict__ v,
                                          int z, int y, int x, int p) {
    float m = -INFINITY;
    #pragma unroll
    for (int dz = -1; dz <= 1; ++dz) {
        int zz = z + dz;
        if (zz < 0 || zz >= D_) continue;
        #pragma unroll
        for (int dy = -1; dy <= 1; ++dy) {
            int yy = y + dy;
            if (yy < 0 || yy >= H_) continue;
            int base = p + dz * HW_ + dy * W_;
            m = fmaxf(m, v[base]);
            if (x > 0)       m = fmaxf(m, v[base - 1]);
            if (x < W_ - 1)  m = fmaxf(m, v[base + 1]);
        }
    }
    return m;
}

// skel = relu(x - dilate(e1)), x read on the fly
__global__ void init_skel_kernel(const float* __restrict__ net,
                                 const int* __restrict__ tgt,
                                 int i0,
                                 const float* __restrict__ e1,
                                 float* __restrict__ skel) {
    int j = blockIdx.y;
    int i = i0 + j;
    int p = blockIdx.x * blockDim.x + threadIdx.x;
    int z = p / HW_;
    int r = p - z * HW_;
    int y = r / W_;
    int x = r - y * W_;
    float o = dilate27(e1 + (long)j * V_, z, y, x, p);
    float xv = load_src(net, tgt, i, p);
    skel[(long)j * V_ + p] = fmaxf(xv - o, 0.0f);
}

// delta = relu(e_cur - dilate(e_next)); skel += relu(delta - skel*delta)
__global__ void update_skel_kernel(const float* __restrict__ e_cur,
                                   const float* __restrict__ e_next,
                                   float* __restrict__ skel) {
    int j = blockIdx.y;
    int p = blockIdx.x * blockDim.x + threadIdx.x;
    int z = p / HW_;
    int r = p - z * HW_;
    int y = r / W_;
    int x = r - y * W_;
    float o = dilate27(e_next + (long)j * V_, z, y, x, p);
    float delta = fmaxf(e_cur[(long)j * V_ + p] - o, 0.0f);
    long idx = (long)j * V_ + p;
    float s = skel[idx];
    skel[idx] = s + fmaxf(delta - s * delta, 0.0f);
}

// Final iteration fused with reduction: compute final skel in-register,
// accumulate sums[2*i] = sum(skel_i * partner_i), sums[2*i+1] = sum(skel_i).
// partner of pred vol i (<4) is gt vol i+4; partner of gt vol i (>=4) is pred i-4.
__global__ void update_reduce_kernel(const float* __restrict__ net,
                                     const int* __restrict__ tgt,
                                     int i0,
                                     const float* __restrict__ e_cur,
                                     const float* __restrict__ e_next,
                                     const float* __restrict__ skel,
                                     double* __restrict__ sums) {
    int j = blockIdx.y;
    int i = i0 + j;
    int p = blockIdx.x * blockDim.x + threadIdx.x;
    int z = p / HW_;
    int r = p - z * HW_;
    int y = r / W_;
    int x = r - y * W_;
    float o = dilate27(e_next + (long)j * V_, z, y, x, p);
    float delta = fmaxf(e_cur[(long)j * V_ + p] - o, 0.0f);
    float s = skel[(long)j * V_ + p];
    float fin = s + fmaxf(delta - s * delta, 0.0f);
    int ipart = (i < 4) ? (i + 4) : (i - 4);
    float partner = load_src(net, tgt, ipart, p);
    float v0 = fin * partner;
    float v1 = fin;
    #pragma unroll
    for (int off = 32; off > 0; off >>= 1) {
        v0 += __shfl_down(v0, off);
        v1 += __shfl_down(v1, off);
    }
    __shared__ float sm[4][2];
    int wid = threadIdx.x >> 6, lane = threadIdx.x & 63;
    if (lane == 0) { sm[wid][0] = v0; sm[wid][1] = v1; }
    __syncthreads();
    if (threadIdx.x == 0) {
        float t0 = 0.f, t1 = 0.f;
        #pragma unroll
        for (int w = 0; w < 4; ++w) { t0 += sm[w][0]; t1 += sm[w][1]; }
        atomicAdd(&sums[2 * i + 0], (double)t0);
        atomicAdd(&sums[2 * i + 1], (double)t1);
    }
}

__global__ void zero_sums_kernel(double* __restrict__ sums) {
    int t = threadIdx.x;
    if (t < 16) sums[t] = 0.0;
}

__global__ void finalize_kernel(const double* __restrict__ sums,
                                float* __restrict__ out) {
    if (threadIdx.x == 0 && blockIdx.x == 0) {
        double acc = 0.0;
        #pragma unroll
        for (int i = 0; i < 4; ++i) {
            double tprec = (sums[2 * i + 0] + SMOOTHF) / (sums[2 * i + 1] + SMOOTHF);
            double tsens = (sums[2 * (i + 4) + 0] + SMOOTHF) / (sums[2 * (i + 4) + 1] + SMOOTHF);
            double cl = (2.0 * tprec * tsens + SMOOTHF) / (tprec + tsens + SMOOTHF);
            acc += cl;
        }
        out[0] = (float)(1.0 - acc * 0.25);
    }
}

extern "C" void kernel_launch(void* const* d_in, const int* in_sizes, int n_in,
                              void* d_out, int out_size, void* d_ws, size_t ws_size,
                              hipStream_t stream) {
    const float* net = (const float*)d_in[0];
    const int* tgt = (const int*)d_in[1];
    float* out = (float*)d_out;

    char* ws = (char*)d_ws;
    double* sums = (double*)ws;                 // 16 doubles
    float* base = (float*)(ws + 256);

    // pick the largest group size G that fits 3*G*V floats in workspace
    size_t perVol = (size_t)3 * V_ * sizeof(float);   // SKEL + E1 + E2 per volume
    int G = 1;
    if (ws_size >= 256 + perVol * 8) G = 8;
    else if (ws_size >= 256 + perVol * 4) G = 4;
    else if (ws_size >= 256 + perVol * 2) G = 2;

    zero_sums_kernel<<<1, 64, 0, stream>>>(sums);

    dim3 block(256);
    dim3 grid(V_ / 256, G);                    // V_ = 12800 * 256 exactly

    for (int i0 = 0; i0 < 8; i0 += G) {
        float* SKEL = base;
        float* E1 = base + (size_t)G * V_;
        float* E2 = E1 + (size_t)G * V_;

        // e1 = erode(x); skel = relu(x - dilate(e1))
        erode_src_kernel<<<grid, block, 0, stream>>>(net, tgt, i0, E1);
        init_skel_kernel<<<grid, block, 0, stream>>>(net, tgt, i0, E1, SKEL);

        // iterations 1..2: e_{k+1} = erode(e_k); skel update
        for (int k = 0; k < 2; ++k) {
            erode_kernel<<<grid, block, 0, stream>>>(E1, E2);
            update_skel_kernel<<<grid, block, 0, stream>>>(E1, E2, SKEL);
            float* t = E1; E1 = E2; E2 = t;
        }
        // iteration 3 fused with reduction (final skel never written)
        erode_kernel<<<grid, block, 0, stream>>>(E1, E2);
        update_reduce_kernel<<<grid, block, 0, stream>>>(net, tgt, i0, E1, E2, SKEL, sums);
    }

    finalize_kernel<<<1, 64, 0, stream>>>(sums, out);
}

// Round 3
// 2023.450 us; speedup vs baseline: 2.1006x; 2.1006x over previous
//
#include <hip/hip_runtime.h>
#include <math.h>

#define D_ 128
#define H_ 160
#define W_ 160
#define HW_ (H_ * W_)            // 25600
#define V_ (D_ * H_ * W_)        // 3,276,800
#define NBLK_ (V_ / 256)         // 12800 blocks per volume (scalar kernels)
#define SMOOTHF 1e-5

// vol index i in 0..7: 0..3 = pred (b = i>>1, ch = (i&1)+1 of net_output),
//                      4..7 = gt one-hot (b = (i-4)>>1, class (i&1)+1 of target)
__device__ __forceinline__ float load_src(const float* __restrict__ net,
                                          const int* __restrict__ tgt,
                                          int i, int p) {
    if (i < 4) {
        int b = i >> 1, c = (i & 1) + 1;
        return net[(long)(b * 3 + c) * V_ + p];
    } else {
        int j = i - 4;
        int b = j >> 1, c = (j & 1) + 1;
        int t = tgt[(long)b * V_ + p];
        t = t < 0 ? 0 : (t > 2 ? 2 : t);
        return (t == c) ? 1.0f : 0.0f;
    }
}

// e1 = erode(src): 7-point cross min, reading source on the fly
__global__ void erode_src_kernel(const float* __restrict__ net,
                                 const int* __restrict__ tgt,
                                 int i0,
                                 float* __restrict__ out) {
    int j = blockIdx.y;
    int i = i0 + j;
    int p = blockIdx.x * blockDim.x + threadIdx.x;
    int z = p / HW_;
    int r = p - z * HW_;
    int y = r / W_;
    int x = r - y * W_;
    float m = load_src(net, tgt, i, p);
    if (z > 0)       m = fminf(m, load_src(net, tgt, i, p - HW_));
    if (z < D_ - 1)  m = fminf(m, load_src(net, tgt, i, p + HW_));
    if (y > 0)       m = fminf(m, load_src(net, tgt, i, p - W_));
    if (y < H_ - 1)  m = fminf(m, load_src(net, tgt, i, p + W_));
    if (x > 0)       m = fminf(m, load_src(net, tgt, i, p - 1));
    if (x < W_ - 1)  m = fminf(m, load_src(net, tgt, i, p + 1));
    out[(long)j * V_ + p] = m;
}

// 7-point cross min, float4-vectorized: each thread owns 4 x-contiguous outputs
__global__ void erode_kernel(const float* __restrict__ in,
                             float* __restrict__ out) {
    int j = blockIdx.y;
    int p4 = blockIdx.x * blockDim.x + threadIdx.x;   // float4 index
    int p = p4 * 4;
    const float* v = in + (long)j * V_;
    int z = p / HW_;
    int r = p - z * HW_;
    int y = r / W_;
    int x = r - y * W_;                                // multiple of 4

    float4 c = *(const float4*)(v + p);
    float lm = (x > 0)      ? v[p - 1] : INFINITY;
    float rm = (x < W_ - 4) ? v[p + 4] : INFINITY;

    float m0 = fminf(c.x, fminf(lm, c.y));
    float m1 = fminf(c.y, fminf(c.x, c.z));
    float m2 = fminf(c.z, fminf(c.y, c.w));
    float m3 = fminf(c.w, fminf(c.z, rm));

    if (y > 0) {
        float4 u = *(const float4*)(v + p - W_);
        m0 = fminf(m0, u.x); m1 = fminf(m1, u.y); m2 = fminf(m2, u.z); m3 = fminf(m3, u.w);
    }
    if (y < H_ - 1) {
        float4 u = *(const float4*)(v + p + W_);
        m0 = fminf(m0, u.x); m1 = fminf(m1, u.y); m2 = fminf(m2, u.z); m3 = fminf(m3, u.w);
    }
    if (z > 0) {
        float4 u = *(const float4*)(v + p - HW_);
        m0 = fminf(m0, u.x); m1 = fminf(m1, u.y); m2 = fminf(m2, u.z); m3 = fminf(m3, u.w);
    }
    if (z < D_ - 1) {
        float4 u = *(const float4*)(v + p + HW_);
        m0 = fminf(m0, u.x); m1 = fminf(m1, u.y); m2 = fminf(m2, u.z); m3 = fminf(m3, u.w);
    }
    float4 o; o.x = m0; o.y = m1; o.z = m2; o.w = m3;
    *(float4*)(out + (long)j * V_ + p) = o;
}

// 27-point max (soft_dilate) of v at (z,y,x) with flat index p
__device__ __forceinline__ float dilate27(const float* __restrict__ v,
                                          int z, int y, int x, int p) {
    float m = -INFINITY;
    #pragma unroll
    for (int dz = -1; dz <= 1; ++dz) {
        int zz = z + dz;
        if (zz < 0 || zz >= D_) continue;
        #pragma unroll
        for (int dy = -1; dy <= 1; ++dy) {
            int yy = y + dy;
            if (yy < 0 || yy >= H_) continue;
            int base = p + dz * HW_ + dy * W_;
            m = fmaxf(m, v[base]);
            if (x > 0)       m = fmaxf(m, v[base - 1]);
            if (x < W_ - 1)  m = fmaxf(m, v[base + 1]);
        }
    }
    return m;
}

// skel = relu(x - dilate(e1)), x read on the fly
__global__ void init_skel_kernel(const float* __restrict__ net,
                                 const int* __restrict__ tgt,
                                 int i0,
                                 const float* __restrict__ e1,
                                 float* __restrict__ skel) {
    int j = blockIdx.y;
    int i = i0 + j;
    int p = blockIdx.x * blockDim.x + threadIdx.x;
    int z = p / HW_;
    int r = p - z * HW_;
    int y = r / W_;
    int x = r - y * W_;
    float o = dilate27(e1 + (long)j * V_, z, y, x, p);
    float xv = load_src(net, tgt, i, p);
    skel[(long)j * V_ + p] = fmaxf(xv - o, 0.0f);
}

// delta = relu(e_cur - dilate(e_next)); skel += relu(delta - skel*delta)
__global__ void update_skel_kernel(const float* __restrict__ e_cur,
                                   const float* __restrict__ e_next,
                                   float* __restrict__ skel) {
    int j = blockIdx.y;
    int p = blockIdx.x * blockDim.x + threadIdx.x;
    int z = p / HW_;
    int r = p - z * HW_;
    int y = r / W_;
    int x = r - y * W_;
    float o = dilate27(e_next + (long)j * V_, z, y, x, p);
    float delta = fmaxf(e_cur[(long)j * V_ + p] - o, 0.0f);
    long idx = (long)j * V_ + p;
    float s = skel[idx];
    skel[idx] = s + fmaxf(delta - s * delta, 0.0f);
}

// Final iteration fused with reduction. Per-block partials -> plain stores
// (NO contended atomics): partials[(i*NBLK_ + blockIdx.x)*2 + {0,1}]
__global__ void update_reduce_kernel(const float* __restrict__ net,
                                     const int* __restrict__ tgt,
                                     int i0,
                                     const float* __restrict__ e_cur,
                                     const float* __restrict__ e_next,
                                     const float* __restrict__ skel,
                                     float* __restrict__ partials) {
    int j = blockIdx.y;
    int i = i0 + j;
    int p = blockIdx.x * blockDim.x + threadIdx.x;
    int z = p / HW_;
    int r = p - z * HW_;
    int y = r / W_;
    int x = r - y * W_;
    float o = dilate27(e_next + (long)j * V_, z, y, x, p);
    float delta = fmaxf(e_cur[(long)j * V_ + p] - o, 0.0f);
    float s = skel[(long)j * V_ + p];
    float fin = s + fmaxf(delta - s * delta, 0.0f);
    int ipart = (i < 4) ? (i + 4) : (i - 4);
    float partner = load_src(net, tgt, ipart, p);
    float v0 = fin * partner;
    float v1 = fin;
    #pragma unroll
    for (int off = 32; off > 0; off >>= 1) {
        v0 += __shfl_down(v0, off);
        v1 += __shfl_down(v1, off);
    }
    __shared__ float sm[4][2];
    int wid = threadIdx.x >> 6, lane = threadIdx.x & 63;
    if (lane == 0) { sm[wid][0] = v0; sm[wid][1] = v1; }
    __syncthreads();
    if (threadIdx.x == 0) {
        float t0 = 0.f, t1 = 0.f;
        #pragma unroll
        for (int w = 0; w < 4; ++w) { t0 += sm[w][0]; t1 += sm[w][1]; }
        long base = ((long)i * NBLK_ + blockIdx.x) * 2;
        partials[base + 0] = t0;
        partials[base + 1] = t1;
    }
}

// one block per volume in group: sum NBLK_ partial pairs in double, write sums
__global__ void reduce_partials_kernel(const float* __restrict__ partials,
                                       int i0,
                                       double* __restrict__ sums) {
    int i = i0 + blockIdx.x;
    double v0 = 0.0, v1 = 0.0;
    for (int b = threadIdx.x; b < NBLK_; b += blockDim.x) {
        long base = ((long)i * NBLK_ + b) * 2;
        v0 += (double)partials[base + 0];
        v1 += (double)partials[base + 1];
    }
    #pragma unroll
    for (int off = 32; off > 0; off >>= 1) {
        v0 += __shfl_down(v0, off);
        v1 += __shfl_down(v1, off);
    }
    __shared__ double sm[16][2];
    int wid = threadIdx.x >> 6, lane = threadIdx.x & 63;
    if (lane == 0) { sm[wid][0] = v0; sm[wid][1] = v1; }
    __syncthreads();
    if (threadIdx.x == 0) {
        double t0 = 0.0, t1 = 0.0;
        int nw = blockDim.x >> 6;
        for (int w = 0; w < nw; ++w) { t0 += sm[w][0]; t1 += sm[w][1]; }
        sums[2 * i + 0] = t0;
        sums[2 * i + 1] = t1;
    }
}

__global__ void finalize_kernel(const double* __restrict__ sums,
                                float* __restrict__ out) {
    if (threadIdx.x == 0 && blockIdx.x == 0) {
        double acc = 0.0;
        #pragma unroll
        for (int i = 0; i < 4; ++i) {
            double tprec = (sums[2 * i + 0] + SMOOTHF) / (sums[2 * i + 1] + SMOOTHF);
            double tsens = (sums[2 * (i + 4) + 0] + SMOOTHF) / (sums[2 * (i + 4) + 1] + SMOOTHF);
            double cl = (2.0 * tprec * tsens + SMOOTHF) / (tprec + tsens + SMOOTHF);
            acc += cl;
        }
        out[0] = (float)(1.0 - acc * 0.25);
    }
}

extern "C" void kernel_launch(void* const* d_in, const int* in_sizes, int n_in,
                              void* d_out, int out_size, void* d_ws, size_t ws_size,
                              hipStream_t stream) {
    const float* net = (const float*)d_in[0];
    const int* tgt = (const int*)d_in[1];
    float* out = (float*)d_out;

    char* ws = (char*)d_ws;
    double* sums = (double*)ws;                           // 16 doubles
    float* partials = (float*)(ws + 256);                 // 8*NBLK_*2 floats
    size_t partials_bytes = (size_t)8 * NBLK_ * 2 * sizeof(float);
    float* base = (float*)(ws + 256 + partials_bytes);

    // pick the largest group size G that fits 3*G*V floats in remaining ws
    size_t head = 256 + partials_bytes;
    size_t perVol = (size_t)3 * V_ * sizeof(float);       // SKEL + E1 + E2
    int G = 1;
    if (ws_size >= head + perVol * 8) G = 8;
    else if (ws_size >= head + perVol * 4) G = 4;
    else if (ws_size >= head + perVol * 2) G = 2;

    dim3 block(256);
    dim3 grid(NBLK_, G);                                  // scalar kernels
    dim3 grid4(V_ / 4 / 256, G);                          // float4 erode

    for (int i0 = 0; i0 < 8; i0 += G) {
        float* SKEL = base;
        float* E1 = base + (size_t)G * V_;
        float* E2 = E1 + (size_t)G * V_;

        erode_src_kernel<<<grid, block, 0, stream>>>(net, tgt, i0, E1);
        init_skel_kernel<<<grid, block, 0, stream>>>(net, tgt, i0, E1, SKEL);

        for (int k = 0; k < 2; ++k) {
            erode_kernel<<<grid4, block, 0, stream>>>(E1, E2);
            update_skel_kernel<<<grid, block, 0, stream>>>(E1, E2, SKEL);
            float* t = E1; E1 = E2; E2 = t;
        }
        erode_kernel<<<grid4, block, 0, stream>>>(E1, E2);
        update_reduce_kernel<<<grid, block, 0, stream>>>(net, tgt, i0, E1, E2, SKEL, partials);
        reduce_partials_kernel<<<G, 1024, 0, stream>>>(partials, i0, sums);
    }

    finalize_kernel<<<1, 64, 0, stream>>>(sums, out);
}

// Round 4
// 808.243 us; speedup vs baseline: 5.2589x; 2.5035x over previous
//
#include <hip/hip_runtime.h>
#include <math.h>

#define D_ 128
#define H_ 160
#define W_ 160
#define HW_ (H_ * W_)            // 25600
#define V_ (D_ * H_ * W_)        // 3,276,800
#define NBLK4_ (V_ / 1024)       // 3200 blocks/volume, 256 thr × 4 elem
#define SMOOTHF 1e-5

__device__ __forceinline__ float max3f(float a, float b, float c) {
    return fmaxf(fmaxf(a, b), c);
}
__device__ __forceinline__ float min3f(float a, float b, float c) {
    return fminf(fminf(a, b), c);
}

// vol index i in 0..7: 0..3 = pred (b = i>>1, ch = (i&1)+1 of net_output),
//                      4..7 = gt one-hot (b = (i-4)>>1, class (i&1)+1 of target)
__device__ __forceinline__ float load_src1(const float* __restrict__ net,
                                           const int* __restrict__ tgt,
                                           int i, int p) {
    if (i < 4) {
        int b = i >> 1, c = (i & 1) + 1;
        return net[(long)(b * 3 + c) * V_ + p];
    } else {
        int j = i - 4;
        int b = j >> 1, c = (j & 1) + 1;
        int t = tgt[(long)b * V_ + p];
        t = t < 0 ? 0 : (t > 2 ? 2 : t);
        return (t == c) ? 1.0f : 0.0f;
    }
}

__device__ __forceinline__ float4 load_src4(const float* __restrict__ net,
                                            const int* __restrict__ tgt,
                                            int i, int p) {
    if (i < 4) {
        int b = i >> 1, c = (i & 1) + 1;
        return *(const float4*)(net + (long)(b * 3 + c) * V_ + p);
    } else {
        int j = i - 4;
        int b = j >> 1, c = (j & 1) + 1;
        int4 t = *(const int4*)(tgt + (long)b * V_ + p);
        float4 o;
        int tx = t.x < 0 ? 0 : (t.x > 2 ? 2 : t.x);
        int ty = t.y < 0 ? 0 : (t.y > 2 ? 2 : t.y);
        int tz = t.z < 0 ? 0 : (t.z > 2 ? 2 : t.z);
        int tw = t.w < 0 ? 0 : (t.w > 2 ? 2 : t.w);
        o.x = (tx == c) ? 1.0f : 0.0f;
        o.y = (ty == c) ? 1.0f : 0.0f;
        o.z = (tz == c) ? 1.0f : 0.0f;
        o.w = (tw == c) ? 1.0f : 0.0f;
        return o;
    }
}

// ---------- erode from source (float4): 7-point cross min ----------
__global__ void erode_src_v4(const float* __restrict__ net,
                             const int* __restrict__ tgt,
                             int i0,
                             float* __restrict__ out) {
    int j = blockIdx.y;
    int i = i0 + j;
    int p4 = blockIdx.x * blockDim.x + threadIdx.x;
    int p = p4 * 4;
    int z = p / HW_;
    int r = p - z * HW_;
    int y = r / W_;
    int x = r - y * W_;                       // multiple of 4

    float4 c = load_src4(net, tgt, i, p);
    float lm = (x > 0)      ? load_src1(net, tgt, i, p - 1) : INFINITY;
    float rm = (x < W_ - 4) ? load_src1(net, tgt, i, p + 4) : INFINITY;

    float m0 = min3f(lm, c.x, c.y);
    float m1 = min3f(c.x, c.y, c.z);
    float m2 = min3f(c.y, c.z, c.w);
    float m3 = min3f(c.z, c.w, rm);

    if (y > 0) {
        float4 u = load_src4(net, tgt, i, p - W_);
        m0 = fminf(m0, u.x); m1 = fminf(m1, u.y); m2 = fminf(m2, u.z); m3 = fminf(m3, u.w);
    }
    if (y < H_ - 1) {
        float4 u = load_src4(net, tgt, i, p + W_);
        m0 = fminf(m0, u.x); m1 = fminf(m1, u.y); m2 = fminf(m2, u.z); m3 = fminf(m3, u.w);
    }
    if (z > 0) {
        float4 u = load_src4(net, tgt, i, p - HW_);
        m0 = fminf(m0, u.x); m1 = fminf(m1, u.y); m2 = fminf(m2, u.z); m3 = fminf(m3, u.w);
    }
    if (z < D_ - 1) {
        float4 u = load_src4(net, tgt, i, p + HW_);
        m0 = fminf(m0, u.x); m1 = fminf(m1, u.y); m2 = fminf(m2, u.z); m3 = fminf(m3, u.w);
    }
    float4 o; o.x = m0; o.y = m1; o.z = m2; o.w = m3;
    *(float4*)(out + (long)j * V_ + p) = o;
}

// ---------- erode from workspace (float4) ----------
__global__ void erode_v4(const float* __restrict__ in,
                         float* __restrict__ out) {
    int j = blockIdx.y;
    int p4 = blockIdx.x * blockDim.x + threadIdx.x;
    int p = p4 * 4;
    const float* v = in + (long)j * V_;
    int z = p / HW_;
    int r = p - z * HW_;
    int y = r / W_;
    int x = r - y * W_;

    float4 c = *(const float4*)(v + p);
    float lm = (x > 0)      ? v[p - 1] : INFINITY;
    float rm = (x < W_ - 4) ? v[p + 4] : INFINITY;

    float m0 = min3f(lm, c.x, c.y);
    float m1 = min3f(c.x, c.y, c.z);
    float m2 = min3f(c.y, c.z, c.w);
    float m3 = min3f(c.z, c.w, rm);

    if (y > 0) {
        float4 u = *(const float4*)(v + p - W_);
        m0 = fminf(m0, u.x); m1 = fminf(m1, u.y); m2 = fminf(m2, u.z); m3 = fminf(m3, u.w);
    }
    if (y < H_ - 1) {
        float4 u = *(const float4*)(v + p + W_);
        m0 = fminf(m0, u.x); m1 = fminf(m1, u.y); m2 = fminf(m2, u.z); m3 = fminf(m3, u.w);
    }
    if (z > 0) {
        float4 u = *(const float4*)(v + p - HW_);
        m0 = fminf(m0, u.x); m1 = fminf(m1, u.y); m2 = fminf(m2, u.z); m3 = fminf(m3, u.w);
    }
    if (z < D_ - 1) {
        float4 u = *(const float4*)(v + p + HW_);
        m0 = fminf(m0, u.x); m1 = fminf(m1, u.y); m2 = fminf(m2, u.z); m3 = fminf(m3, u.w);
    }
    float4 o; o.x = m0; o.y = m1; o.z = m2; o.w = m3;
    *(float4*)(out + (long)j * V_ + p) = o;
}

// ---------- 27-point dilate, float4: per (dz,dy) row 1 float4 + 2 scalars ----------
__device__ __forceinline__ float4 dilate27_v4(const float* __restrict__ v,
                                              int z, int y, int x, int p) {
    float m0 = -INFINITY, m1 = -INFINITY, m2 = -INFINITY, m3 = -INFINITY;
    #pragma unroll
    for (int dz = -1; dz <= 1; ++dz) {
        int zz = z + dz;
        if (zz < 0 || zz >= D_) continue;
        #pragma unroll
        for (int dy = -1; dy <= 1; ++dy) {
            int yy = y + dy;
            if (yy < 0 || yy >= H_) continue;
            int base = p + dz * HW_ + dy * W_;
            float4 c = *(const float4*)(v + base);
            float lm = (x > 0)      ? v[base - 1] : -INFINITY;
            float rm = (x < W_ - 4) ? v[base + 4] : -INFINITY;
            m0 = fmaxf(m0, max3f(lm, c.x, c.y));
            m1 = fmaxf(m1, max3f(c.x, c.y, c.z));
            m2 = fmaxf(m2, max3f(c.y, c.z, c.w));
            m3 = fmaxf(m3, max3f(c.z, c.w, rm));
        }
    }
    float4 o; o.x = m0; o.y = m1; o.z = m2; o.w = m3;
    return o;
}

// ---------- skel = relu(x - dilate(e1)) ----------
__global__ void init_skel_v4(const float* __restrict__ net,
                             const int* __restrict__ tgt,
                             int i0,
                             const float* __restrict__ e1,
                             float* __restrict__ skel) {
    int j = blockIdx.y;
    int i = i0 + j;
    int p4 = blockIdx.x * blockDim.x + threadIdx.x;
    int p = p4 * 4;
    int z = p / HW_;
    int r = p - z * HW_;
    int y = r / W_;
    int x = r - y * W_;
    float4 o = dilate27_v4(e1 + (long)j * V_, z, y, x, p);
    float4 xv = load_src4(net, tgt, i, p);
    float4 s;
    s.x = fmaxf(xv.x - o.x, 0.0f);
    s.y = fmaxf(xv.y - o.y, 0.0f);
    s.z = fmaxf(xv.z - o.z, 0.0f);
    s.w = fmaxf(xv.w - o.w, 0.0f);
    *(float4*)(skel + (long)j * V_ + p) = s;
}

// ---------- delta = relu(e_cur - dilate(e_next)); skel += relu(delta - skel*delta) ----------
__global__ void update_skel_v4(const float* __restrict__ e_cur,
                               const float* __restrict__ e_next,
                               float* __restrict__ skel) {
    int j = blockIdx.y;
    int p4 = blockIdx.x * blockDim.x + threadIdx.x;
    int p = p4 * 4;
    int z = p / HW_;
    int r = p - z * HW_;
    int y = r / W_;
    int x = r - y * W_;
    float4 o = dilate27_v4(e_next + (long)j * V_, z, y, x, p);
    float4 ec = *(const float4*)(e_cur + (long)j * V_ + p);
    long idx = (long)j * V_ + p;
    float4 s = *(const float4*)(skel + idx);
    float d0 = fmaxf(ec.x - o.x, 0.0f);
    float d1 = fmaxf(ec.y - o.y, 0.0f);
    float d2 = fmaxf(ec.z - o.z, 0.0f);
    float d3 = fmaxf(ec.w - o.w, 0.0f);
    s.x += fmaxf(d0 - s.x * d0, 0.0f);
    s.y += fmaxf(d1 - s.y * d1, 0.0f);
    s.z += fmaxf(d2 - s.z * d2, 0.0f);
    s.w += fmaxf(d3 - s.w * d3, 0.0f);
    *(float4*)(skel + idx) = s;
}

// ---------- final iteration fused with reduction (per-block partials) ----------
__global__ void update_reduce_v4(const float* __restrict__ net,
                                 const int* __restrict__ tgt,
                                 int i0,
                                 const float* __restrict__ e_cur,
                                 const float* __restrict__ e_next,
                                 const float* __restrict__ skel,
                                 float* __restrict__ partials) {
    int j = blockIdx.y;
    int i = i0 + j;
    int p4 = blockIdx.x * blockDim.x + threadIdx.x;
    int p = p4 * 4;
    int z = p / HW_;
    int r = p - z * HW_;
    int y = r / W_;
    int x = r - y * W_;
    float4 o = dilate27_v4(e_next + (long)j * V_, z, y, x, p);
    float4 ec = *(const float4*)(e_cur + (long)j * V_ + p);
    float4 s = *(const float4*)(skel + (long)j * V_ + p);
    float d0 = fmaxf(ec.x - o.x, 0.0f);
    float d1 = fmaxf(ec.y - o.y, 0.0f);
    float d2 = fmaxf(ec.z - o.z, 0.0f);
    float d3 = fmaxf(ec.w - o.w, 0.0f);
    float f0 = s.x + fmaxf(d0 - s.x * d0, 0.0f);
    float f1 = s.y + fmaxf(d1 - s.y * d1, 0.0f);
    float f2 = s.z + fmaxf(d2 - s.z * d2, 0.0f);
    float f3 = s.w + fmaxf(d3 - s.w * d3, 0.0f);
    int ipart = (i < 4) ? (i + 4) : (i - 4);
    float4 pr = load_src4(net, tgt, ipart, p);
    float v0 = f0 * pr.x + f1 * pr.y + f2 * pr.z + f3 * pr.w;
    float v1 = f0 + f1 + f2 + f3;
    #pragma unroll
    for (int off = 32; off > 0; off >>= 1) {
        v0 += __shfl_down(v0, off);
        v1 += __shfl_down(v1, off);
    }
    __shared__ float sm[4][2];
    int wid = threadIdx.x >> 6, lane = threadIdx.x & 63;
    if (lane == 0) { sm[wid][0] = v0; sm[wid][1] = v1; }
    __syncthreads();
    if (threadIdx.x == 0) {
        float t0 = 0.f, t1 = 0.f;
        #pragma unroll
        for (int w = 0; w < 4; ++w) { t0 += sm[w][0]; t1 += sm[w][1]; }
        long base = ((long)i * NBLK4_ + blockIdx.x) * 2;
        partials[base + 0] = t0;
        partials[base + 1] = t1;
    }
}

// one block per volume in group: sum partial pairs in double, write sums
__global__ void reduce_partials_kernel(const float* __restrict__ partials,
                                       int i0,
                                       double* __restrict__ sums) {
    int i = i0 + blockIdx.x;
    double v0 = 0.0, v1 = 0.0;
    for (int b = threadIdx.x; b < NBLK4_; b += blockDim.x) {
        long base = ((long)i * NBLK4_ + b) * 2;
        v0 += (double)partials[base + 0];
        v1 += (double)partials[base + 1];
    }
    #pragma unroll
    for (int off = 32; off > 0; off >>= 1) {
        v0 += __shfl_down(v0, off);
        v1 += __shfl_down(v1, off);
    }
    __shared__ double sm[16][2];
    int wid = threadIdx.x >> 6, lane = threadIdx.x & 63;
    if (lane == 0) { sm[wid][0] = v0; sm[wid][1] = v1; }
    __syncthreads();
    if (threadIdx.x == 0) {
        double t0 = 0.0, t1 = 0.0;
        int nw = blockDim.x >> 6;
        for (int w = 0; w < nw; ++w) { t0 += sm[w][0]; t1 += sm[w][1]; }
        sums[2 * i + 0] = t0;
        sums[2 * i + 1] = t1;
    }
}

__global__ void finalize_kernel(const double* __restrict__ sums,
                                float* __restrict__ out) {
    if (threadIdx.x == 0 && blockIdx.x == 0) {
        double acc = 0.0;
        #pragma unroll
        for (int i = 0; i < 4; ++i) {
            double tprec = (sums[2 * i + 0] + SMOOTHF) / (sums[2 * i + 1] + SMOOTHF);
            double tsens = (sums[2 * (i + 4) + 0] + SMOOTHF) / (sums[2 * (i + 4) + 1] + SMOOTHF);
            double cl = (2.0 * tprec * tsens + SMOOTHF) / (tprec + tsens + SMOOTHF);
            acc += cl;
        }
        out[0] = (float)(1.0 - acc * 0.25);
    }
}

extern "C" void kernel_launch(void* const* d_in, const int* in_sizes, int n_in,
                              void* d_out, int out_size, void* d_ws, size_t ws_size,
                              hipStream_t stream) {
    const float* net = (const float*)d_in[0];
    const int* tgt = (const int*)d_in[1];
    float* out = (float*)d_out;

    char* ws = (char*)d_ws;
    double* sums = (double*)ws;                           // 16 doubles
    float* partials = (float*)(ws + 256);                 // 8*NBLK4_*2 floats
    size_t partials_bytes = (size_t)8 * NBLK4_ * 2 * sizeof(float);
    float* base = (float*)(ws + 256 + partials_bytes);

    size_t head = 256 + partials_bytes;
    size_t perVol = (size_t)3 * V_ * sizeof(float);       // SKEL + E1 + E2
    int G = 1;
    if (ws_size >= head + perVol * 8) G = 8;
    else if (ws_size >= head + perVol * 4) G = 4;
    else if (ws_size >= head + perVol * 2) G = 2;

    dim3 block(256);
    dim3 grid4(NBLK4_, G);

    for (int i0 = 0; i0 < 8; i0 += G) {
        float* SKEL = base;
        float* E1 = base + (size_t)G * V_;
        float* E2 = E1 + (size_t)G * V_;

        erode_src_v4<<<grid4, block, 0, stream>>>(net, tgt, i0, E1);
        init_skel_v4<<<grid4, block, 0, stream>>>(net, tgt, i0, E1, SKEL);

        for (int k = 0; k < 2; ++k) {
            erode_v4<<<grid4, block, 0, stream>>>(E1, E2);
            update_skel_v4<<<grid4, block, 0, stream>>>(E1, E2, SKEL);
            float* t = E1; E1 = E2; E2 = t;
        }
        erode_v4<<<grid4, block, 0, stream>>>(E1, E2);
        update_reduce_v4<<<grid4, block, 0, stream>>>(net, tgt, i0, E1, E2, SKEL, partials);
        reduce_partials_kernel<<<G, 1024, 0, stream>>>(partials, i0, sums);
    }

    finalize_kernel<<<1, 64, 0, stream>>>(sums, out);
}

// Round 5
// 658.484 us; speedup vs baseline: 6.4549x; 1.2274x over previous
//
#include <hip/hip_runtime.h>
#include <math.h>

#define D_ 128
#define H_ 160
#define W_ 160
#define HW_ (H_ * W_)            // 25600
#define V_ (D_ * H_ * W_)        // 3,276,800
#define SMOOTHF 1e-5

#define TY 8                      // output rows per block
#define ZC 32                     // z-chunk per block
#define NYT (H_ / TY)             // 20
#define NZC (D_ / ZC)             // 4
#define NTB (NYT * NZC)           // 80 tiles per volume
#define NT 320                    // threads per block (5 waves)
#define AROWS (TY + 4)            // 12 rows: y0-2 .. y0+9 (e_cur / src)
#define BROWS (TY + 2)            // 10 rows: y0-1 .. y0+8 (e_next / xm)
#define APLANE (AROWS * W_)       // 1920 floats
#define BPLANE (BROWS * W_)       // 1600 floats

__device__ __forceinline__ float max3f(float a, float b, float c) {
    return fmaxf(fmaxf(a, b), c);
}
__device__ __forceinline__ int slot3(int z) { return ((z % 3) + 3) % 3; }

// vol i in 0..7: 0..3 = pred (b=i>>1, ch=(i&1)+1), 4..7 = gt one-hot
__device__ __forceinline__ float4 load_src4(const float* __restrict__ net,
                                            const int* __restrict__ tgt,
                                            int i, int p) {
    if (i < 4) {
        int b = i >> 1, c = (i & 1) + 1;
        return *(const float4*)(net + (long)(b * 3 + c) * V_ + p);
    } else {
        int j = i - 4;
        int b = j >> 1, c = (j & 1) + 1;
        int4 t = *(const int4*)(tgt + (long)b * V_ + p);
        float4 o;
        int tx = t.x < 0 ? 0 : (t.x > 2 ? 2 : t.x);
        int ty = t.y < 0 ? 0 : (t.y > 2 ? 2 : t.y);
        int tz = t.z < 0 ? 0 : (t.z > 2 ? 2 : t.z);
        int tw = t.w < 0 ? 0 : (t.w > 2 ? 2 : t.w);
        o.x = (tx == c) ? 1.0f : 0.0f;
        o.y = (ty == c) ? 1.0f : 0.0f;
        o.z = (tz == c) ? 1.0f : 0.0f;
        o.w = (tw == c) ? 1.0f : 0.0f;
        return o;
    }
}

// VAR: 0 = INIT  (src -> e_out, skel = relu(src - dilate(e_out)))
//      1 = UPDATE(e_in -> e_out, skel += relu(d - skel*d), d = relu(e_in - dilate(e_out)))
//      2 = FINAL (e_in -> (in LDS only), fin = skel + relu(d - skel*d), reduce vs partner)
template <int VAR>
__global__ __launch_bounds__(NT) void fused_iter(
    const float* __restrict__ net, const int* __restrict__ tgt, int i0,
    const float* __restrict__ e_in, float* __restrict__ e_out,
    float* __restrict__ skel, float* __restrict__ partials) {
    __shared__ float A[3][APLANE];    // e_cur/src ring, rows y0-2..y0+9
    __shared__ float E[BPLANE];       // e_next current plane, rows y0-1..y0+8
    __shared__ float XM[3][BPLANE];   // x-max(e_next) ring
    __shared__ float smr[5][2];

    const int j = blockIdx.y;
    const int i = i0 + j;
    const int bx = blockIdx.x;
    const int ty = bx % NYT, zc = bx / NYT;
    const int y0 = ty * TY, z0 = zc * ZC;
    const int tid = threadIdx.x;

    const float* ein_v = (VAR != 0) ? e_in + (long)j * V_ : nullptr;
    float* eout_v = (VAR != 2) ? e_out + (long)j * V_ : nullptr;
    float* skel_v = skel + (long)j * V_;

    // dilate/output coords: thread owns float4 at (y0+orow, ox)
    const int orow = tid / 40;
    const int ox4 = tid - orow * 40;
    const int ox = ox4 * 4;

    float acc0 = 0.f, acc1 = 0.f;

    for (int s = z0 - 2; s <= z0 + 33; ++s) {
        __syncthreads();   // protect A/XM ring slot reuse vs previous step's readers

        // ---- stage 1: load A plane s ----
        {
            float* Ap = A[slot3(s)];
            const bool zok = (s >= 0 && s < D_);
            for (int idx = tid; idx < APLANE / 4; idx += NT) {
                int row = idx / 40;
                int x4 = idx - row * 40;
                int g = y0 - 2 + row;
                float4 v;
                if (!zok || g < 0 || g >= H_) {
                    v = make_float4(INFINITY, INFINITY, INFINITY, INFINITY);
                } else {
                    int p = s * HW_ + g * W_ + x4 * 4;
                    if (VAR == 0) v = load_src4(net, tgt, i, p);
                    else          v = *(const float4*)(ein_v + p);
                }
                ((float4*)Ap)[idx] = v;
            }
        }
        __syncthreads();

        // ---- stage 2: compute E = erode(A) for plane s-1 ----
        if (s >= z0) {
            const int zz = s - 1;
            if (zz < 0 || zz >= D_) {
                for (int idx = tid; idx < BPLANE / 4; idx += NT)
                    ((float4*)E)[idx] = make_float4(-INFINITY, -INFINITY, -INFINITY, -INFINITY);
            } else {
                const float* A0 = A[slot3(zz - 1)];
                const float* A1 = A[slot3(zz)];
                const float* A2 = A[slot3(zz + 1)];
                for (int idx = tid; idx < BPLANE / 4; idx += NT) {
                    int row = idx / 40;
                    int x4 = idx - row * 40;
                    int x = x4 * 4;
                    int g = y0 - 1 + row;
                    float4 e;
                    if (g < 0 || g >= H_) {
                        e = make_float4(-INFINITY, -INFINITY, -INFINITY, -INFINITY);
                    } else {
                        int o = (row + 1) * W_ + x;   // A row index for global g
                        float4 c1 = *(const float4*)(A1 + o);
                        float4 c0 = *(const float4*)(A0 + o);
                        float4 c2 = *(const float4*)(A2 + o);
                        float4 u  = *(const float4*)(A1 + o - W_);
                        float4 d  = *(const float4*)(A1 + o + W_);
                        float lm = (x > 0)       ? A1[o - 1] : INFINITY;
                        float rm = (x < W_ - 4)  ? A1[o + 4] : INFINITY;
                        e.x = fminf(fminf(fminf(c1.x, lm),  c1.y), fminf(fminf(u.x, d.x), fminf(c0.x, c2.x)));
                        e.y = fminf(fminf(fminf(c1.y, c1.x), c1.z), fminf(fminf(u.y, d.y), fminf(c0.y, c2.y)));
                        e.z = fminf(fminf(fminf(c1.z, c1.y), c1.w), fminf(fminf(u.z, d.z), fminf(c0.z, c2.z)));
                        e.w = fminf(fminf(fminf(c1.w, c1.z), rm),   fminf(fminf(u.w, d.w), fminf(c0.w, c2.w)));
                    }
                    ((float4*)E)[idx] = e;
                }
            }
        }
        __syncthreads();

        // ---- stage 3: xm = max3_x(E) into ring; write e_out interior ----
        if (s >= z0) {
            const int zz = s - 1;
            float* Xp = XM[slot3(zz)];
            for (int idx = tid; idx < BPLANE / 4; idx += NT) {
                int row = idx / 40;
                int x4 = idx - row * 40;
                int x = x4 * 4;
                const float* q = E + row * W_ + x;
                float4 c = *(const float4*)q;
                float lm = (x > 0)      ? q[-1] : -INFINITY;
                float rm = (x < W_ - 4) ? q[4]  : -INFINITY;
                float4 xm;
                xm.x = max3f(lm, c.x, c.y);
                xm.y = max3f(c.x, c.y, c.z);
                xm.z = max3f(c.y, c.z, c.w);
                xm.w = max3f(c.z, c.w, rm);
                ((float4*)Xp)[idx] = xm;
            }
            if (VAR != 2 && zz >= z0 && zz < z0 + ZC) {
                // interior rows y0..y0+TY-1 = E rows 1..TY; 320 f4 = NT exactly
                int row = tid / 40;
                int x4 = tid - row * 40;
                ((float4*)(eout_v + zz * HW_ + (y0 + row) * W_))[x4] =
                    ((const float4*)(E + (row + 1) * W_))[x4];
            }
        }
        __syncthreads();

        // ---- stage 4: dilate from XM (9 taps) + skel update at plane s-2 ----
        if (s >= z0 + 2) {
            const int z = s - 2;
            float4 m = make_float4(-INFINITY, -INFINITY, -INFINITY, -INFINITY);
            #pragma unroll
            for (int pl = 0; pl < 3; ++pl) {
                const float* Xp = XM[slot3(z - 1 + pl)];
                #pragma unroll
                for (int dr = 0; dr < 3; ++dr) {
                    float4 t = *(const float4*)(Xp + (orow + dr) * W_ + ox);
                    m.x = fmaxf(m.x, t.x); m.y = fmaxf(m.y, t.y);
                    m.z = fmaxf(m.z, t.z); m.w = fmaxf(m.w, t.w);
                }
            }
            // center value (src for INIT, e_cur otherwise) from A plane z
            const float* Ac = A[slot3(z)] + (orow + 2) * W_ + ox;
            float4 cv = *(const float4*)Ac;
            long gp = (long)z * HW_ + (y0 + orow) * W_ + ox;
            if (VAR == 0) {
                float4 sv;
                sv.x = fmaxf(cv.x - m.x, 0.f);
                sv.y = fmaxf(cv.y - m.y, 0.f);
                sv.z = fmaxf(cv.z - m.z, 0.f);
                sv.w = fmaxf(cv.w - m.w, 0.f);
                *(float4*)(skel_v + gp) = sv;
            } else if (VAR == 1) {
                float4 sv = *(const float4*)(skel_v + gp);
                float d0 = fmaxf(cv.x - m.x, 0.f);
                float d1 = fmaxf(cv.y - m.y, 0.f);
                float d2 = fmaxf(cv.z - m.z, 0.f);
                float d3 = fmaxf(cv.w - m.w, 0.f);
                sv.x += fmaxf(d0 - sv.x * d0, 0.f);
                sv.y += fmaxf(d1 - sv.y * d1, 0.f);
                sv.z += fmaxf(d2 - sv.z * d2, 0.f);
                sv.w += fmaxf(d3 - sv.w * d3, 0.f);
                *(float4*)(skel_v + gp) = sv;
            } else {
                float4 sv = *(const float4*)(skel_v + gp);
                float d0 = fmaxf(cv.x - m.x, 0.f);
                float d1 = fmaxf(cv.y - m.y, 0.f);
                float d2 = fmaxf(cv.z - m.z, 0.f);
                float d3 = fmaxf(cv.w - m.w, 0.f);
                float f0 = sv.x + fmaxf(d0 - sv.x * d0, 0.f);
                float f1 = sv.y + fmaxf(d1 - sv.y * d1, 0.f);
                float f2 = sv.z + fmaxf(d2 - sv.z * d2, 0.f);
                float f3 = sv.w + fmaxf(d3 - sv.w * d3, 0.f);
                int ipart = (i < 4) ? (i + 4) : (i - 4);
                float4 pr = load_src4(net, tgt, ipart, (int)gp);
                acc0 += f0 * pr.x + f1 * pr.y + f2 * pr.z + f3 * pr.w;
                acc1 += f0 + f1 + f2 + f3;
            }
        }
    }

    if (VAR == 2) {
        #pragma unroll
        for (int off = 32; off > 0; off >>= 1) {
            acc0 += __shfl_down(acc0, off);
            acc1 += __shfl_down(acc1, off);
        }
        int wid = tid >> 6, lane = tid & 63;
        __syncthreads();
        if (lane == 0) { smr[wid][0] = acc0; smr[wid][1] = acc1; }
        __syncthreads();
        if (tid == 0) {
            float t0 = 0.f, t1 = 0.f;
            #pragma unroll
            for (int w = 0; w < 5; ++w) { t0 += smr[w][0]; t1 += smr[w][1]; }
            long base = ((long)i * NTB + bx) * 2;
            partials[base + 0] = t0;
            partials[base + 1] = t1;
        }
    }
}

// one block per volume: sum NTB partial pairs in double
__global__ void reduce_partials_kernel(const float* __restrict__ partials,
                                       int i0,
                                       double* __restrict__ sums) {
    int i = i0 + blockIdx.x;
    int t = threadIdx.x;   // 128
    double v0 = 0.0, v1 = 0.0;
    for (int b = t; b < NTB; b += blockDim.x) {
        long base = ((long)i * NTB + b) * 2;
        v0 += (double)partials[base + 0];
        v1 += (double)partials[base + 1];
    }
    #pragma unroll
    for (int off = 32; off > 0; off >>= 1) {
        v0 += __shfl_down(v0, off);
        v1 += __shfl_down(v1, off);
    }
    __shared__ double sm[2][2];
    int wid = t >> 6, lane = t & 63;
    if (lane == 0) { sm[wid][0] = v0; sm[wid][1] = v1; }
    __syncthreads();
    if (t == 0) {
        sums[2 * i + 0] = sm[0][0] + sm[1][0];
        sums[2 * i + 1] = sm[0][1] + sm[1][1];
    }
}

__global__ void finalize_kernel(const double* __restrict__ sums,
                                float* __restrict__ out) {
    if (threadIdx.x == 0 && blockIdx.x == 0) {
        double acc = 0.0;
        #pragma unroll
        for (int i = 0; i < 4; ++i) {
            double tprec = (sums[2 * i + 0] + SMOOTHF) / (sums[2 * i + 1] + SMOOTHF);
            double tsens = (sums[2 * (i + 4) + 0] + SMOOTHF) / (sums[2 * (i + 4) + 1] + SMOOTHF);
            double cl = (2.0 * tprec * tsens + SMOOTHF) / (tprec + tsens + SMOOTHF);
            acc += cl;
        }
        out[0] = (float)(1.0 - acc * 0.25);
    }
}

extern "C" void kernel_launch(void* const* d_in, const int* in_sizes, int n_in,
                              void* d_out, int out_size, void* d_ws, size_t ws_size,
                              hipStream_t stream) {
    const float* net = (const float*)d_in[0];
    const int* tgt = (const int*)d_in[1];
    float* out = (float*)d_out;

    char* ws = (char*)d_ws;
    double* sums = (double*)ws;                     // 16 doubles
    float* partials = (float*)(ws + 256);           // 8*NTB*2 floats = 5120 B
    size_t head = 256 + (size_t)8 * NTB * 2 * sizeof(float);
    head = (head + 255) & ~(size_t)255;
    float* base = (float*)(ws + head);

    size_t perVol = (size_t)3 * V_ * sizeof(float); // SKEL + E1 + E2
    int G = 1;
    if (ws_size >= head + perVol * 8) G = 8;
    else if (ws_size >= head + perVol * 4) G = 4;
    else if (ws_size >= head + perVol * 2) G = 2;

    dim3 blk(NT);
    dim3 grd(NTB, G);

    for (int i0 = 0; i0 < 8; i0 += G) {
        float* SKEL = base;
        float* E1 = base + (size_t)G * V_;
        float* E2 = E1 + (size_t)G * V_;

        // e1 = erode(x); skel = relu(x - dilate(e1))
        fused_iter<0><<<grd, blk, 0, stream>>>(net, tgt, i0, nullptr, E1, SKEL, nullptr);
        // iter 1: e2 = erode(e1); skel update
        fused_iter<1><<<grd, blk, 0, stream>>>(net, tgt, i0, E1, E2, SKEL, nullptr);
        // iter 2: e3 = erode(e2); skel update
        fused_iter<1><<<grd, blk, 0, stream>>>(net, tgt, i0, E2, E1, SKEL, nullptr);
        // iter 3 fused with reduction (e4 and final skel never hit memory)
        fused_iter<2><<<grd, blk, 0, stream>>>(net, tgt, i0, E1, nullptr, SKEL, partials);

        reduce_partials_kernel<<<G, 128, 0, stream>>>(partials, i0, sums);
    }

    finalize_kernel<<<1, 64, 0, stream>>>(sums, out);
}

// Round 6
// 593.236 us; speedup vs baseline: 7.1649x; 1.1100x over previous
//
#include <hip/hip_runtime.h>
#include <math.h>

#define D_ 128
#define H_ 160
#define W_ 160
#define HW_ (H_ * W_)            // 25600
#define V_ (D_ * H_ * W_)        // 3,276,800
#define SMOOTHF 1e-5

#define TY 8                      // output rows per block
#define ZC 16                     // z-planes per block
#define NYT (H_ / TY)             // 20
#define NZC (D_ / ZC)             // 8
#define NTB (NYT * NZC)           // 160 tiles per volume
#define NT 320                    // threads (5 waves); 8 rows x 40 f4 = 320
#define W4 (W_ / 4)               // 40
#define RIN 14                    // IN rows: y0-3 .. y0+10
#define RE1 12                    // E1 rows: y0-2 .. y0+9
#define RE2 10                    // E2 rows: y0-1 .. y0+8

__device__ __forceinline__ float max3f(float a, float b, float c) {
    return fmaxf(fmaxf(a, b), c);
}
__device__ __forceinline__ float min3f(float a, float b, float c) {
    return fminf(fminf(a, b), c);
}
__device__ __forceinline__ float cross7(float m3, float yu, float yd, float zu, float zd) {
    return fminf(fminf(fminf(m3, yu), fminf(yd, zu)), zd);
}
__device__ __forceinline__ int slot3(int z) { return ((z % 3) + 3) % 3; }
__device__ __forceinline__ int slot5(int z) { return ((z % 5) + 5) % 5; }

// vol i in 0..7: 0..3 = pred (b=i>>1, ch=(i&1)+1), 4..7 = gt one-hot
__device__ __forceinline__ float4 load_src4(const float* __restrict__ net,
                                            const int* __restrict__ tgt,
                                            int i, int p) {
    if (i < 4) {
        int b = i >> 1, c = (i & 1) + 1;
        return *(const float4*)(net + (long)(b * 3 + c) * V_ + p);
    } else {
        int j = i - 4;
        int b = j >> 1, c = (j & 1) + 1;
        int4 t = *(const int4*)(tgt + (long)b * V_ + p);
        float4 o;
        int tx = t.x < 0 ? 0 : (t.x > 2 ? 2 : t.x);
        int ty = t.y < 0 ? 0 : (t.y > 2 ? 2 : t.y);
        int tz = t.z < 0 ? 0 : (t.z > 2 ? 2 : t.z);
        int tw = t.w < 0 ? 0 : (t.w > 2 ? 2 : t.w);
        o.x = (tx == c) ? 1.0f : 0.0f;
        o.y = (ty == c) ? 1.0f : 0.0f;
        o.z = (tz == c) ? 1.0f : 0.0f;
        o.w = (tw == c) ? 1.0f : 0.0f;
        return o;
    }
}

// Two skeleton iterations fused, z-marching.
// VAR 0 (A): IN = src (on the fly). Computes e1, e2. Writes e2 -> e_out and
//            skel = U(relu(src - dil(e1)), delta1 = relu(e1 - dil(e2))).
// VAR 1 (B): IN = e2 (global). Computes e3, e4 (LDS only). Updates skel with
//            delta2 = relu(e2 - dil(e3)), delta3 = relu(e3 - dil(e4)),
//            reduces fin vs partner into per-block partials. No volume writes.
template <int VAR>
__global__ __launch_bounds__(NT) void fused_pair(
    const float* __restrict__ net, const int* __restrict__ tgt, int i0,
    const float* __restrict__ e_in, float* __restrict__ e_out,
    float* __restrict__ skel, float* __restrict__ partials) {
    __shared__ float IN[5][RIN * W_];    // input ring (src or e2)
    __shared__ float E1[3][RE1 * W_];    // first erosion ring (e1 or e3)
    __shared__ float E2[RE2 * W_];       // second erosion plane (e2 or e4)
    __shared__ float smr[NT / 64][2];

    const int j = blockIdx.y;
    const int i = i0 + j;
    const int bx = blockIdx.x;
    const int ty = bx % NYT, zcid = bx / NYT;
    const int y0 = ty * TY, z0 = zcid * ZC;
    const int tid = threadIdx.x;
    const int orow = tid / W4;           // 0..7
    const int ox4 = tid - orow * W4;     // 0..39
    const int ox = ox4 * 4;

    const float* ein_v = (VAR == 1) ? e_in + (long)j * V_ : nullptr;
    float* eout_v = (VAR == 0) ? e_out + (long)j * V_ : nullptr;
    float* skel_v = skel + (long)j * V_;

    const float4 inf4 = make_float4(INFINITY, INFINITY, INFINITY, INFINITY);
    const float4 ninf4 = make_float4(-INFINITY, -INFINITY, -INFINITY, -INFINITY);

    // xym register rings (per-thread column at (y0+orow, ox..ox+3))
    float4 r0 = ninf4, r1 = ninf4, r2 = ninf4;   // xym1: P(s-4),P(s-3),P(s-2)
    float4 q0 = ninf4, q1 = ninf4;               // xym2: Q(s-4),Q(s-3)
    float acc0 = 0.f, acc1 = 0.f;

    for (int s = z0 - 3; s <= z0 + ZC + 2; ++s) {
        // ---- stage 1: load IN plane s (+INF outside volume: erode identity)
        {
            float* Ap = IN[slot5(s)];
            const bool zok = (s >= 0 && s < D_);
            #pragma unroll
            for (int idx = tid; idx < RIN * W4; idx += NT) {
                int row = idx / W4, x4 = idx - row * W4;
                int g = y0 - 3 + row;
                float4 v;
                if (!zok || g < 0 || g >= H_) v = inf4;
                else {
                    int p = s * HW_ + g * W_ + x4 * 4;
                    v = (VAR == 0) ? load_src4(net, tgt, i, p)
                                   : *(const float4*)(ein_v + p);
                }
                ((float4*)Ap)[idx] = v;
            }
        }
        __syncthreads();   // B1: IN(s) ready

        // ---- stage 2: E1(zz1 = s-1) = erode(IN)
        if (s >= z0 - 1) {
            const int zz1 = s - 1;
            float* Ep = E1[slot3(zz1)];
            if (zz1 < 0 || zz1 >= D_) {
                #pragma unroll
                for (int idx = tid; idx < RE1 * W4; idx += NT)
                    ((float4*)Ep)[idx] = ninf4;   // dilate-friendly fill
            } else {
                const float* A0 = IN[slot5(zz1 - 1)];
                const float* A1 = IN[slot5(zz1)];
                const float* A2 = IN[slot5(zz1 + 1)];
                #pragma unroll
                for (int idx = tid; idx < RE1 * W4; idx += NT) {
                    int row = idx / W4, x4 = idx - row * W4, x = x4 * 4;
                    int g = y0 - 2 + row;
                    float4 e;
                    if (g < 0 || g >= H_) e = ninf4;
                    else {
                        int o = (row + 1) * W_ + x;       // IN local row = row+1
                        float4 c  = *(const float4*)(A1 + o);
                        float4 yu = *(const float4*)(A1 + o - W_);
                        float4 yd = *(const float4*)(A1 + o + W_);
                        float4 zu = *(const float4*)(A0 + o);
                        float4 zd = *(const float4*)(A2 + o);
                        float lm = (x > 0)      ? A1[o - 1] : INFINITY;
                        float rm = (x < W_ - 4) ? A1[o + 4] : INFINITY;
                        e.x = cross7(min3f(lm, c.x, c.y), yu.x, yd.x, zu.x, zd.x);
                        e.y = cross7(min3f(c.x, c.y, c.z), yu.y, yd.y, zu.y, zd.y);
                        e.z = cross7(min3f(c.y, c.z, c.w), yu.z, yd.z, zu.z, zd.z);
                        e.w = cross7(min3f(c.z, c.w, rm),  yu.w, yd.w, zu.w, zd.w);
                    }
                    ((float4*)Ep)[idx] = e;
                }
            }
        }
        __syncthreads();   // B2: E1(s-1) ready

        // ---- stage 3: fresh1 = xym1(s-1) (registers; rows orow+1..orow+3 of E1)
        float4 fresh1 = ninf4;
        if (s >= z0 - 1) {
            const float* Ep = E1[slot3(s - 1)];
            #pragma unroll
            for (int dr = 0; dr < 3; ++dr) {
                const float* q = Ep + (orow + 1 + dr) * W_ + ox;
                float4 c = *(const float4*)q;
                float lm = (ox > 0)       ? q[-1] : -INFINITY;
                float rm = (ox < W_ - 4)  ? q[4]  : -INFINITY;
                fresh1.x = fmaxf(fresh1.x, max3f(lm, c.x, c.y));
                fresh1.y = fmaxf(fresh1.y, max3f(c.x, c.y, c.z));
                fresh1.z = fmaxf(fresh1.z, max3f(c.y, c.z, c.w));
                fresh1.w = fmaxf(fresh1.w, max3f(c.z, c.w, rm));
            }
        }

        // ---- stage 4: E2(zz2 = s-2) = erode(E1)
        if (s >= z0 + 1) {
            const int zz2 = s - 2;
            if (zz2 < 0 || zz2 >= D_) {
                #pragma unroll
                for (int idx = tid; idx < RE2 * W4; idx += NT)
                    ((float4*)E2)[idx] = ninf4;
            } else {
                const float* B0 = E1[slot3(zz2 - 1)];
                const float* B1p = E1[slot3(zz2)];
                const float* B2p = E1[slot3(zz2 + 1)];
                const bool zmok = (zz2 - 1 >= 0), zpok = (zz2 + 1 < D_);
                #pragma unroll
                for (int idx = tid; idx < RE2 * W4; idx += NT) {
                    int row = idx / W4, x4 = idx - row * W4, x = x4 * 4;
                    int g = y0 - 1 + row;
                    float4 e;
                    if (g < 0 || g >= H_) e = ninf4;
                    else {
                        int o = (row + 1) * W_ + x;      // E1 local row = row+1
                        float4 c  = *(const float4*)(B1p + o);
                        float4 yu = (g - 1 >= 0) ? *(const float4*)(B1p + o - W_) : inf4;
                        float4 yd = (g + 1 < H_) ? *(const float4*)(B1p + o + W_) : inf4;
                        float4 zu = zmok ? *(const float4*)(B0 + o) : inf4;
                        float4 zd = zpok ? *(const float4*)(B2p + o) : inf4;
                        float lm = (x > 0)      ? B1p[o - 1] : INFINITY;
                        float rm = (x < W_ - 4) ? B1p[o + 4] : INFINITY;
                        e.x = cross7(min3f(lm, c.x, c.y), yu.x, yd.x, zu.x, zd.x);
                        e.y = cross7(min3f(c.x, c.y, c.z), yu.y, yd.y, zu.y, zd.y);
                        e.z = cross7(min3f(c.y, c.z, c.w), yu.z, yd.z, zu.z, zd.z);
                        e.w = cross7(min3f(c.z, c.w, rm),  yu.w, yd.w, zu.w, zd.w);
                    }
                    ((float4*)E2)[idx] = e;
                }
            }
        }
        __syncthreads();   // B3: E2(s-2) ready

        // ---- stage 5: fresh2 = xym2(s-2) (rows orow..orow+2 of E2)
        float4 fresh2 = ninf4;
        if (s >= z0 + 1) {
            #pragma unroll
            for (int dr = 0; dr < 3; ++dr) {
                const float* q = E2 + (orow + dr) * W_ + ox;
                float4 c = *(const float4*)q;
                float lm = (ox > 0)       ? q[-1] : -INFINITY;
                float rm = (ox < W_ - 4)  ? q[4]  : -INFINITY;
                fresh2.x = fmaxf(fresh2.x, max3f(lm, c.x, c.y));
                fresh2.y = fmaxf(fresh2.y, max3f(c.x, c.y, c.z));
                fresh2.z = fmaxf(fresh2.z, max3f(c.y, c.z, c.w));
                fresh2.w = fmaxf(fresh2.w, max3f(c.z, c.w, rm));
            }
            // e2 interior write (kernel A only), plane zz2
            if (VAR == 0) {
                const int zz2 = s - 2;
                if (zz2 >= z0 && zz2 < z0 + ZC) {
                    ((float4*)(eout_v + zz2 * HW_ + (y0 + orow) * W_))[ox4] =
                        ((const float4*)(E2 + (orow + 1) * W_))[ox4];
                }
            }
        }

        // ---- stage 6: output plane z = s-3
        if (s >= z0 + 3) {
            const int z = s - 3;
            float4 dil1, dil2;
            dil1.x = max3f(r0.x, r1.x, r2.x);
            dil1.y = max3f(r0.y, r1.y, r2.y);
            dil1.z = max3f(r0.z, r1.z, r2.z);
            dil1.w = max3f(r0.w, r1.w, r2.w);
            dil2.x = max3f(q0.x, q1.x, fresh2.x);
            dil2.y = max3f(q0.y, q1.y, fresh2.y);
            dil2.z = max3f(q0.z, q1.z, fresh2.z);
            dil2.w = max3f(q0.w, q1.w, fresh2.w);
            float4 cin = *(const float4*)(IN[slot5(z)] + (orow + 3) * W_ + ox);
            float4 ce1 = *(const float4*)(E1[slot3(z)] + (orow + 2) * W_ + ox);
            long gp = (long)z * HW_ + (y0 + orow) * W_ + ox;
            if (VAR == 0) {
                // s0 = relu(src - dil(e1)); d1 = relu(e1 - dil(e2)); U(s0,d1)
                float s0x = fmaxf(cin.x - dil1.x, 0.f);
                float s0y = fmaxf(cin.y - dil1.y, 0.f);
                float s0z = fmaxf(cin.z - dil1.z, 0.f);
                float s0w = fmaxf(cin.w - dil1.w, 0.f);
                float d1x = fmaxf(ce1.x - dil2.x, 0.f);
                float d1y = fmaxf(ce1.y - dil2.y, 0.f);
                float d1z = fmaxf(ce1.z - dil2.z, 0.f);
                float d1w = fmaxf(ce1.w - dil2.w, 0.f);
                float4 sk;
                sk.x = s0x + fmaxf(d1x - s0x * d1x, 0.f);
                sk.y = s0y + fmaxf(d1y - s0y * d1y, 0.f);
                sk.z = s0z + fmaxf(d1z - s0z * d1z, 0.f);
                sk.w = s0w + fmaxf(d1w - s0w * d1w, 0.f);
                *(float4*)(skel_v + gp) = sk;
            } else {
                float4 sv = *(const float4*)(skel_v + gp);
                // d2 = relu(e2 - dil(e3)); s' = U(s, d2)
                float d2x = fmaxf(cin.x - dil1.x, 0.f);
                float d2y = fmaxf(cin.y - dil1.y, 0.f);
                float d2z = fmaxf(cin.z - dil1.z, 0.f);
                float d2w = fmaxf(cin.w - dil1.w, 0.f);
                float spx = sv.x + fmaxf(d2x - sv.x * d2x, 0.f);
                float spy = sv.y + fmaxf(d2y - sv.y * d2y, 0.f);
                float spz = sv.z + fmaxf(d2z - sv.z * d2z, 0.f);
                float spw = sv.w + fmaxf(d2w - sv.w * d2w, 0.f);
                // d3 = relu(e3 - dil(e4)); fin = U(s', d3)
                float d3x = fmaxf(ce1.x - dil2.x, 0.f);
                float d3y = fmaxf(ce1.y - dil2.y, 0.f);
                float d3z = fmaxf(ce1.z - dil2.z, 0.f);
                float d3w = fmaxf(ce1.w - dil2.w, 0.f);
                float f0 = spx + fmaxf(d3x - spx * d3x, 0.f);
                float f1 = spy + fmaxf(d3y - spy * d3y, 0.f);
                float f2 = spz + fmaxf(d3z - spz * d3z, 0.f);
                float f3 = spw + fmaxf(d3w - spw * d3w, 0.f);
                int ipart = (i < 4) ? (i + 4) : (i - 4);
                float4 pr = load_src4(net, tgt, ipart, (int)gp);
                acc0 += f0 * pr.x + f1 * pr.y + f2 * pr.z + f3 * pr.w;
                acc1 += f0 + f1 + f2 + f3;
            }
        }

        // ring shifts
        r0 = r1; r1 = r2; r2 = fresh1;
        q0 = q1; q1 = fresh2;
    }

    if (VAR == 1) {
        #pragma unroll
        for (int off = 32; off > 0; off >>= 1) {
            acc0 += __shfl_down(acc0, off);
            acc1 += __shfl_down(acc1, off);
        }
        int wid = tid >> 6, lane = tid & 63;
        __syncthreads();
        if (lane == 0) { smr[wid][0] = acc0; smr[wid][1] = acc1; }
        __syncthreads();
        if (tid == 0) {
            float t0 = 0.f, t1 = 0.f;
            #pragma unroll
            for (int w = 0; w < NT / 64; ++w) { t0 += smr[w][0]; t1 += smr[w][1]; }
            long base = ((long)i * NTB + bx) * 2;
            partials[base + 0] = t0;
            partials[base + 1] = t1;
        }
    }
}

__global__ void reduce_partials_kernel(const float* __restrict__ partials,
                                       int i0,
                                       double* __restrict__ sums) {
    int i = i0 + blockIdx.x;
    int t = threadIdx.x;   // 128
    double v0 = 0.0, v1 = 0.0;
    for (int b = t; b < NTB; b += blockDim.x) {
        long base = ((long)i * NTB + b) * 2;
        v0 += (double)partials[base + 0];
        v1 += (double)partials[base + 1];
    }
    #pragma unroll
    for (int off = 32; off > 0; off >>= 1) {
        v0 += __shfl_down(v0, off);
        v1 += __shfl_down(v1, off);
    }
    __shared__ double sm[2][2];
    int wid = t >> 6, lane = t & 63;
    if (lane == 0) { sm[wid][0] = v0; sm[wid][1] = v1; }
    __syncthreads();
    if (t == 0) {
        sums[2 * i + 0] = sm[0][0] + sm[1][0];
        sums[2 * i + 1] = sm[0][1] + sm[1][1];
    }
}

__global__ void finalize_kernel(const double* __restrict__ sums,
                                float* __restrict__ out) {
    if (threadIdx.x == 0 && blockIdx.x == 0) {
        double acc = 0.0;
        #pragma unroll
        for (int i = 0; i < 4; ++i) {
            double tprec = (sums[2 * i + 0] + SMOOTHF) / (sums[2 * i + 1] + SMOOTHF);
            double tsens = (sums[2 * (i + 4) + 0] + SMOOTHF) / (sums[2 * (i + 4) + 1] + SMOOTHF);
            double cl = (2.0 * tprec * tsens + SMOOTHF) / (tprec + tsens + SMOOTHF);
            acc += cl;
        }
        out[0] = (float)(1.0 - acc * 0.25);
    }
}

extern "C" void kernel_launch(void* const* d_in, const int* in_sizes, int n_in,
                              void* d_out, int out_size, void* d_ws, size_t ws_size,
                              hipStream_t stream) {
    const float* net = (const float*)d_in[0];
    const int* tgt = (const int*)d_in[1];
    float* out = (float*)d_out;

    char* ws = (char*)d_ws;
    double* sums = (double*)ws;                      // 16 doubles
    float* partials = (float*)(ws + 256);            // 8*NTB*2 floats
    size_t head = 256 + (size_t)8 * NTB * 2 * sizeof(float);
    head = (head + 255) & ~(size_t)255;
    float* base = (float*)(ws + head);

    size_t perVol = (size_t)2 * V_ * sizeof(float);  // SKEL + E2 per volume
    int G = 1;
    if (ws_size >= head + perVol * 8) G = 8;
    else if (ws_size >= head + perVol * 4) G = 4;
    else if (ws_size >= head + perVol * 2) G = 2;

    dim3 blk(NT);
    dim3 grd(NTB, G);

    for (int i0 = 0; i0 < 8; i0 += G) {
        float* SKEL = base;
        float* E2buf = base + (size_t)G * V_;

        // A: src -> e2, skel (after iterations 0 and 1)
        fused_pair<0><<<grd, blk, 0, stream>>>(net, tgt, i0, nullptr, E2buf, SKEL, nullptr);
        // B: e2 -> (e3,e4 in LDS), final skel in-register, reduce
        fused_pair<1><<<grd, blk, 0, stream>>>(net, tgt, i0, E2buf, nullptr, SKEL, partials);

        reduce_partials_kernel<<<G, 128, 0, stream>>>(partials, i0, sums);
    }

    finalize_kernel<<<1, 64, 0, stream>>>(sums, out);
}

// Round 7
// 377.001 us; speedup vs baseline: 11.2745x; 1.5736x over previous
//
#include <hip/hip_runtime.h>
#include <math.h>

#define D_ 128
#define H_ 160
#define W_ 160
#define HW_ (H_ * W_)            // 25600
#define V_ (D_ * H_ * W_)        // 3,276,800
#define SMOOTHF 1e-5

#define R_ 16                    // rows covered per block (TY + 6 halo)
#define TY 10                    // output rows per block
#define ZC 32                    // z-planes produced per block
#define COLS 40                  // float4 columns (W_/4)
#define NT 640                   // R_ * COLS threads (10 waves)
#define LROW 41                  // padded row length in float4 (164 floats)
#define NYT 16                   // H_/TY
#define NZC 4                    // D_/ZC
#define NTB (NYT * NZC)          // 64 tiles per volume

__device__ __forceinline__ float max3f(float a, float b, float c) { return fmaxf(fmaxf(a, b), c); }
__device__ __forceinline__ float min3f(float a, float b, float c) { return fminf(fminf(a, b), c); }
__device__ __forceinline__ float4 f4min(float4 a, float4 b) {
    return make_float4(fminf(a.x,b.x), fminf(a.y,b.y), fminf(a.z,b.z), fminf(a.w,b.w));
}
__device__ __forceinline__ float4 f4max(float4 a, float4 b) {
    return make_float4(fmaxf(a.x,b.x), fmaxf(a.y,b.y), fmaxf(a.z,b.z), fmaxf(a.w,b.w));
}
// sliding 3-window min/max along x of (l | c | r)
__device__ __forceinline__ float4 min3x(float l, float4 c, float r) {
    return make_float4(min3f(l,c.x,c.y), min3f(c.x,c.y,c.z), min3f(c.y,c.z,c.w), min3f(c.z,c.w,r));
}
__device__ __forceinline__ float4 max3x(float l, float4 c, float r) {
    return make_float4(max3f(l,c.x,c.y), max3f(c.x,c.y,c.z), max3f(c.y,c.z,c.w), max3f(c.z,c.w,r));
}
__device__ __forceinline__ float4 relu4sub(float4 a, float4 b) {   // relu(a-b)
    return make_float4(fmaxf(a.x-b.x,0.f), fmaxf(a.y-b.y,0.f), fmaxf(a.z-b.z,0.f), fmaxf(a.w-b.w,0.f));
}
__device__ __forceinline__ float4 skel_upd(float4 s, float4 d) {   // s + relu(d - s*d)
    return make_float4(s.x + fmaxf(d.x - s.x*d.x, 0.f), s.y + fmaxf(d.y - s.y*d.y, 0.f),
                       s.z + fmaxf(d.z - s.z*d.z, 0.f), s.w + fmaxf(d.w - s.w*d.w, 0.f));
}

// vol i in 0..7: 0..3 = pred (b=i>>1, ch=(i&1)+1), 4..7 = gt one-hot
__device__ __forceinline__ float4 load_src4(const float* __restrict__ net,
                                            const int* __restrict__ tgt,
                                            int i, long p) {
    if (i < 4) {
        int b = i >> 1, c = (i & 1) + 1;
        return *(const float4*)(net + (long)(b * 3 + c) * V_ + p);
    } else {
        int j = i - 4;
        int b = j >> 1, c = (j & 1) + 1;
        int4 t = *(const int4*)(tgt + (long)b * V_ + p);
        float4 o;
        int tx = t.x < 0 ? 0 : (t.x > 2 ? 2 : t.x);
        int ty = t.y < 0 ? 0 : (t.y > 2 ? 2 : t.y);
        int tz = t.z < 0 ? 0 : (t.z > 2 ? 2 : t.z);
        int tw = t.w < 0 ? 0 : (t.w > 2 ? 2 : t.w);
        o.x = (tx == c) ? 1.0f : 0.0f;
        o.y = (ty == c) ? 1.0f : 0.0f;
        o.z = (tz == c) ? 1.0f : 0.0f;
        o.w = (tw == c) ? 1.0f : 0.0f;
        return o;
    }
}

// Two skeleton iterations fused, thread-per-column z-march.
// VAR 0 (A): IN = src. Writes e2 volume + skel (after iters 0,1).
// VAR 1 (B): IN = e2. e3,e4 never leave the block; final skel in-register;
//            reduces fin vs partner into per-block partials. No volume writes.
template <int VAR>
__global__ __launch_bounds__(NT, 5) void fused_pair(
    const float* __restrict__ net, const int* __restrict__ tgt, int i0,
    const float* __restrict__ e_in, float* __restrict__ e_out,
    float* __restrict__ skel, float* __restrict__ partials) {

    __shared__ float4 Pb[2][R_ * LROW];
    __shared__ float4 E1b[2][R_ * LROW];
    __shared__ float4 E2b[R_ * LROW];
    __shared__ float smr[NT / 64][2];

    const int j = blockIdx.y, i = i0 + j;
    const int bx = blockIdx.x;
    const int y0 = (bx % NYT) * TY;
    const int z0 = (bx / NYT) * ZC;
    const int tid = threadIdx.x;
    const int r  = tid / COLS;         // 0..15
    const int x4 = tid - r * COLS;     // 0..39
    const int y  = y0 - 3 + r;
    const bool yok  = (y >= 0 && y < H_);
    const bool ymok = (y - 1 >= 0 && y - 1 < H_);
    const bool ypok = (y + 1 >= 0 && y + 1 < H_);
    const int rm = (r > 0) ? r - 1 : 0;
    const int rp = (r < R_ - 1) ? r + 1 : R_ - 1;
    const int xm = (x4 > 0) ? x4 - 1 : 0;
    const int xp = (x4 < COLS - 1) ? x4 + 1 : COLS - 1;
    const bool fxm = (x4 > 0), fxp = (x4 < COLS - 1);
    const bool rout = (r >= 3 && r < 3 + TY);
    const long colbase = (long)(yok ? y : 0) * W_ + x4 * 4;

    const float* ein_v = (VAR == 1) ? e_in + (long)j * V_ : nullptr;
    float* eout_v = (VAR == 0) ? e_out + (long)j * V_ : nullptr;
    float* skel_v = skel + (long)j * V_;
    const int ipart = (i < 4) ? (i + 4) : (i - 4);

    const float4 INF4  = make_float4( INFINITY,  INFINITY,  INFINITY,  INFINITY);
    const float4 NINF4 = make_float4(-INFINITY, -INFINITY, -INFINITY, -INFINITY);

    // register rings (per-thread column)
    float4 a0 = INF4, a1 = INF4, a2 = INF4;           // P(s-3), P(s-2), P(s-1)
    float4 e11 = NINF4, e12 = NINF4;                  // e1(s-3), e1(s-2)
    float4 x1a = NINF4, x1b = NINF4;                  // xym1(s-4), xym1(s-3)
    float4 x2a = NINF4, x2b = NINF4;                  // xym2(s-4), xym2(s-3)
    float4 psk = make_float4(0,0,0,0), ppr = make_float4(0,0,0,0);
    float acc0 = 0.f, acc1 = 0.f;

    for (int s = z0 - 3; s <= z0 + ZC + 2; ++s) {
        // ---- W0: load input plane s; prefetch skel/partner for z=s-3 (VAR1)
        float4 anew;
        {
            const bool zok = (s >= 0 && s < D_);
            float4 v = INF4;
            if (zok && yok) {
                long p = (long)s * HW_ + colbase;
                v = (VAR == 0) ? load_src4(net, tgt, i, p)
                               : *(const float4*)(ein_v + p);
            }
            Pb[s & 1][r * LROW + x4] = v;
            anew = v;
            if (VAR == 1) {
                int z3 = s - 3;
                if (z3 >= z0 && z3 < z0 + ZC && rout) {
                    long p = (long)z3 * HW_ + colbase;
                    psk = *(const float4*)(skel_v + p);
                    ppr = load_src4(net, tgt, ipart, p);
                }
            }
        }
        __syncthreads();

        // ---- W1: e1(s-1) = 7-pt cross erode of IN
        float4 fe1;
        {
            const int z1 = s - 1;
            const bool z1ok = (z1 >= 0 && z1 < D_);
            const float4* Pp = Pb[z1 & 1];
            float4 up = Pp[rm * LROW + x4];
            float4 dn = Pp[rp * LROW + x4];
            float lf = Pp[r * LROW + xm].w;
            float rt = Pp[r * LROW + xp].x;
            if (!ymok) up = INF4;
            if (!ypok) dn = INF4;
            if (!fxm) lf = INFINITY;
            if (!fxp) rt = INFINITY;
            float4 e = f4min(f4min(min3x(lf, a2, rt), f4min(up, dn)), f4min(a1, anew));
            if (!z1ok || !yok) e = NINF4;
            fe1 = e;
            E1b[z1 & 1][r * LROW + x4] = e;
        }
        __syncthreads();

        // ---- W2: e2(s-2) (cross erode of e1) + xym1(s-2) (3x3 xy-max of e1)
        float4 fe2, f1;
        {
            const int z2 = s - 2;
            const bool z2ok = (z2 >= 0 && z2 < D_);
            const float4* Ep = E1b[z2 & 1];
            float4 n00 = Ep[rm*LROW+xm], n01 = Ep[rm*LROW+x4], n02 = Ep[rm*LROW+xp];
            float4 n10 = Ep[r *LROW+xm],                        n12 = Ep[r *LROW+xp];
            float4 n20 = Ep[rp*LROW+xm], n21 = Ep[rp*LROW+x4], n22 = Ep[rp*LROW+xp];
            float4 c = e12;
            // erode cross (min identities = +INF)
            {
                float4 up = ymok ? n01 : INF4;
                float4 dn = ypok ? n21 : INF4;
                float lf = fxm ? n10.w : INFINITY;
                float rt = fxp ? n12.x : INFINITY;
                float4 zu = (z2 >= 1)     ? e11 : INF4;
                float4 zd = (z2 + 1 < D_) ? fe1 : INF4;
                float4 e = f4min(f4min(min3x(lf, c, rt), f4min(up, dn)), f4min(zu, zd));
                if (!z2ok || !yok) e = NINF4;
                fe2 = e;
            }
            // xym1 (max identities = -INF; y-pad rows already -INF in LDS)
            {
                float l0 = fxm ? n00.w : -INFINITY, r0 = fxp ? n02.x : -INFINITY;
                float l1 = fxm ? n10.w : -INFINITY, r1 = fxp ? n12.x : -INFINITY;
                float l2 = fxm ? n20.w : -INFINITY, r2 = fxp ? n22.x : -INFINITY;
                float4 m = f4max(f4max(max3x(l0, n01, r0), max3x(l1, c, r1)), max3x(l2, n21, r2));
                if (!z2ok) m = NINF4;
                f1 = m;
            }
            E2b[r * LROW + x4] = fe2;
            if (VAR == 0 && z2 >= z0 && z2 < z0 + ZC && rout) {
                *(float4*)(eout_v + (long)z2 * HW_ + colbase) = fe2;
            }
        }
        __syncthreads();

        // ---- W3: xym2(s-2) + output plane z = s-3
        float4 f2;
        {
            float4 m00 = E2b[rm*LROW+xm], m01 = E2b[rm*LROW+x4], m02 = E2b[rm*LROW+xp];
            float4 m10 = E2b[r *LROW+xm],                         m12 = E2b[r *LROW+xp];
            float4 m20 = E2b[rp*LROW+xm], m21 = E2b[rp*LROW+x4], m22 = E2b[rp*LROW+xp];
            float l0 = fxm ? m00.w : -INFINITY, r0 = fxp ? m02.x : -INFINITY;
            float l1 = fxm ? m10.w : -INFINITY, r1 = fxp ? m12.x : -INFINITY;
            float l2 = fxm ? m20.w : -INFINITY, r2 = fxp ? m22.x : -INFINITY;
            f2 = f4max(f4max(max3x(l0, m01, r0), max3x(l1, fe2, r1)), max3x(l2, m21, r2));
        }
        {
            const int z3 = s - 3;
            if (z3 >= z0 && z3 < z0 + ZC && rout) {
                float4 dil1 = f4max(f4max(x1a, x1b), f1);
                float4 dil2 = f4max(f4max(x2a, x2b), f2);
                float4 cin = a0, ce1 = e11;
                long p = (long)z3 * HW_ + colbase;
                if (VAR == 0) {
                    float4 s0 = relu4sub(cin, dil1);        // relu(src - dil(e1))
                    float4 d1 = relu4sub(ce1, dil2);        // relu(e1 - dil(e2))
                    *(float4*)(skel_v + p) = skel_upd(s0, d1);
                } else {
                    float4 d2 = relu4sub(cin, dil1);        // relu(e2 - dil(e3))
                    float4 sp = skel_upd(psk, d2);
                    float4 d3 = relu4sub(ce1, dil2);        // relu(e3 - dil(e4))
                    float4 fin = skel_upd(sp, d3);
                    acc0 += fin.x * ppr.x + fin.y * ppr.y + fin.z * ppr.z + fin.w * ppr.w;
                    acc1 += fin.x + fin.y + fin.z + fin.w;
                }
            }
        }
        // ring shifts
        a0 = a1; a1 = a2; a2 = anew;
        e11 = e12; e12 = fe1;
        x1a = x1b; x1b = f1;
        x2a = x2b; x2b = f2;
    }

    if (VAR == 1) {
        #pragma unroll
        for (int off = 32; off > 0; off >>= 1) {
            acc0 += __shfl_down(acc0, off);
            acc1 += __shfl_down(acc1, off);
        }
        int wid = tid >> 6, lane = tid & 63;
        __syncthreads();
        if (lane == 0) { smr[wid][0] = acc0; smr[wid][1] = acc1; }
        __syncthreads();
        if (tid == 0) {
            float t0 = 0.f, t1 = 0.f;
            #pragma unroll
            for (int w = 0; w < NT / 64; ++w) { t0 += smr[w][0]; t1 += smr[w][1]; }
            long base = ((long)i * NTB + bx) * 2;
            partials[base + 0] = t0;
            partials[base + 1] = t1;
        }
    }
}

// one block (64 threads) per volume: sum NTB=64 partial pairs in double
__global__ void reduce_partials_kernel(const float* __restrict__ partials,
                                       int i0,
                                       double* __restrict__ sums) {
    int i = i0 + blockIdx.x;
    int t = threadIdx.x;    // 64
    long base = ((long)i * NTB + t) * 2;
    double v0 = (double)partials[base + 0];
    double v1 = (double)partials[base + 1];
    #pragma unroll
    for (int off = 32; off > 0; off >>= 1) {
        v0 += __shfl_down(v0, off);
        v1 += __shfl_down(v1, off);
    }
    if (t == 0) {
        sums[2 * i + 0] = v0;
        sums[2 * i + 1] = v1;
    }
}

__global__ void finalize_kernel(const double* __restrict__ sums,
                                float* __restrict__ out) {
    if (threadIdx.x == 0 && blockIdx.x == 0) {
        double acc = 0.0;
        #pragma unroll
        for (int i = 0; i < 4; ++i) {
            double tprec = (sums[2 * i + 0] + SMOOTHF) / (sums[2 * i + 1] + SMOOTHF);
            double tsens = (sums[2 * (i + 4) + 0] + SMOOTHF) / (sums[2 * (i + 4) + 1] + SMOOTHF);
            double cl = (2.0 * tprec * tsens + SMOOTHF) / (tprec + tsens + SMOOTHF);
            acc += cl;
        }
        out[0] = (float)(1.0 - acc * 0.25);
    }
}

extern "C" void kernel_launch(void* const* d_in, const int* in_sizes, int n_in,
                              void* d_out, int out_size, void* d_ws, size_t ws_size,
                              hipStream_t stream) {
    const float* net = (const float*)d_in[0];
    const int* tgt = (const int*)d_in[1];
    float* out = (float*)d_out;

    char* ws = (char*)d_ws;
    double* sums = (double*)ws;                      // 16 doubles
    float* partials = (float*)(ws + 256);            // 8*NTB*2 floats
    size_t head = 256 + (size_t)8 * NTB * 2 * sizeof(float);
    head = (head + 255) & ~(size_t)255;
    float* base = (float*)(ws + head);

    size_t perVol = (size_t)2 * V_ * sizeof(float);  // SKEL + E2 per volume
    int G = 1;
    if (ws_size >= head + perVol * 8) G = 8;
    else if (ws_size >= head + perVol * 4) G = 4;
    else if (ws_size >= head + perVol * 2) G = 2;

    dim3 blk(NT);
    dim3 grd(NTB, G);

    for (int i0 = 0; i0 < 8; i0 += G) {
        float* SKEL = base;
        float* E2buf = base + (size_t)G * V_;

        // A: src -> e2 volume + skel (iterations 0,1)
        fused_pair<0><<<grd, blk, 0, stream>>>(net, tgt, i0, nullptr, E2buf, SKEL, nullptr);
        // B: e2 -> (e3,e4 in LDS/regs), final skel in-register, reduce
        fused_pair<1><<<grd, blk, 0, stream>>>(net, tgt, i0, E2buf, nullptr, SKEL, partials);

        reduce_partials_kernel<<<G, 64, 0, stream>>>(partials, i0, sums);
    }

    finalize_kernel<<<1, 64, 0, stream>>>(sums, out);
}